// Round 1
// baseline (1041.037 us; speedup 1.0000x reference)
//
#include <hip/hip_runtime.h>

#define NBIN  25
#define BATCH 16
#define DROWS 100000
#define DIM   128

constexpr float DELTA_F = 2.0f / 24.0f;   // 2/(NBIN-1), matches fp32 reference
constexpr int   NWAVES  = 4;
constexpr int   BLOCK   = NWAVES * 64;    // 256 threads
constexpr int   GRIDX   = 128;            // blocks per batch -> 2048 blocks total

// ---------------------------------------------------------------------------
// Kernel 1: per-batch soft histograms.
// Layout: blockIdx.y = batch b, blockIdx.x strides over row groups.
// Each 32-lane half-wave owns one db row; lane `sub` loads float4 at elem 4*sub
// (16B/lane, wave reads 1KB contiguous covering 2 adjacent rows). Butterfly
// shfl-reduce gives dot(q,d) and |d|^2 to all lanes of the half.
// ---------------------------------------------------------------------------
__global__ __launch_bounds__(BLOCK) void qap_hist_kernel(
    const float* __restrict__ qX, const float* __restrict__ dXs,
    const int* __restrict__ labels, float* __restrict__ ws)
{
    const int b    = blockIdx.y;
    const int tid  = threadIdx.x;
    const int wave = tid >> 6;
    const int lane = tid & 63;
    const int half = lane >> 5;
    const int sub  = lane & 31;

    __shared__ float sh_lab[NWAVES][NBIN];
    __shared__ float sh_all[NWAVES][NBIN];
    __shared__ float sh_labsum;

    for (int i = tid; i < NWAVES * NBIN; i += BLOCK) {
        (&sh_lab[0][0])[i] = 0.0f;
        (&sh_all[0][0])[i] = 0.0f;
    }
    if (tid == 0) sh_labsum = 0.0f;
    __syncthreads();

    // Per-lane q fragment (reused every row) + |q| reduced across the half.
    const float4 qv = *reinterpret_cast<const float4*>(qX + b * DIM + sub * 4);
    float qn2 = qv.x * qv.x + qv.y * qv.y + qv.z * qv.z + qv.w * qv.w;
    #pragma unroll
    for (int m = 1; m < 32; m <<= 1) qn2 += __shfl_xor(qn2, m);
    const float qn = sqrtf(qn2);

    const size_t dbase = (size_t)b * DROWS;
    float labcount = 0.0f;

    const int rowStride = GRIDX * NWAVES * 2;  // rows consumed per grid pass
    for (int base = blockIdx.x * (NWAVES * 2); base < DROWS; base += rowStride) {
        const int r = base + wave * 2 + half;
        float dot = 0.0f, nrm = 0.0f;
        if (r < DROWS) {
            const float4 dv = *reinterpret_cast<const float4*>(
                dXs + (dbase + (size_t)r) * DIM + sub * 4);
            dot = qv.x * dv.x + qv.y * dv.y + qv.z * dv.z + qv.w * dv.w;
            nrm = dv.x * dv.x + dv.y * dv.y + dv.z * dv.z + dv.w * dv.w;
        }
        #pragma unroll
        for (int m = 1; m < 32; m <<= 1) {
            dot += __shfl_xor(dot, m);
            nrm += __shfl_xor(nrm, m);
        }
        if (sub == 0 && r < DROWS) {
            const float dn  = sqrtf(nrm);
            const float sim = dot / fmaxf(qn * dn, 1e-8f);
            // Triangular kernel: sim falls between centers m0 and m0+1.
            const float t  = (1.0f - sim) / DELTA_F;
            const int   m0 = (int)floorf(t);
            const float w1 = t - (float)m0;
            const float w0 = 1.0f - w1;
            const int lab = labels[dbase + (size_t)r];
            if ((unsigned)m0 < NBIN) {
                atomicAdd(&sh_all[wave][m0], w0);
                if (lab) atomicAdd(&sh_lab[wave][m0], w0);
            }
            if ((unsigned)(m0 + 1) < NBIN) {
                atomicAdd(&sh_all[wave][m0 + 1], w1);
                if (lab) atomicAdd(&sh_lab[wave][m0 + 1], w1);
            }
            labcount += (float)lab;
        }
    }

    if (sub == 0) atomicAdd(&sh_labsum, labcount);
    __syncthreads();

    float* g_lab    = ws;
    float* g_all    = ws + BATCH * NBIN;
    float* g_labsum = ws + 2 * BATCH * NBIN;
    if (tid < NBIN) {
        float sl = 0.0f, sa = 0.0f;
        #pragma unroll
        for (int w = 0; w < NWAVES; ++w) { sl += sh_lab[w][tid]; sa += sh_all[w][tid]; }
        atomicAdd(&g_lab[b * NBIN + tid], sl);
        atomicAdd(&g_all[b * NBIN + tid], sa);
    }
    if (tid == BLOCK - 1) atomicAdd(&g_labsum[b], sh_labsum);
}

// ---------------------------------------------------------------------------
// Kernel 2: tiny epilogue. Thread b does the 25-bin cumsum / precision /
// recall serially; butterfly-reduce the 16 APQ values; write the scalar mean.
// ---------------------------------------------------------------------------
__global__ void qap_finalize_kernel(const float* __restrict__ ws,
                                    float* __restrict__ out)
{
    const int b = threadIdx.x;
    float apq = 0.0f;
    if (b < BATCH) {
        const float* hl = ws + b * NBIN;
        const float* ha = ws + BATCH * NBIN + b * NBIN;
        const float labsum = ws[2 * BATCH * NBIN + b];
        float cl = 0.0f, ca = 0.0f, s = 0.0f;
        for (int n = 0; n < NBIN; ++n) {
            cl += hl[n];
            ca += ha[n];
            const float prec = cl / (ca + 1e-16f);
            const float rec  = hl[n] / labsum;
            s += prec * rec;
        }
        apq = s * (1.0f / (float)NBIN);
    }
    #pragma unroll
    for (int m = 1; m < 16; m <<= 1) apq += __shfl_xor(apq, m);
    if (threadIdx.x == 0) out[0] = apq * (1.0f / (float)BATCH);
}

extern "C" void kernel_launch(void* const* d_in, const int* in_sizes, int n_in,
                              void* d_out, int out_size, void* d_ws, size_t ws_size,
                              hipStream_t stream) {
    const float* qX     = (const float*)d_in[0];
    const float* dXs    = (const float*)d_in[1];
    const int*   labels = (const int*)d_in[2];
    float*       out    = (float*)d_out;
    float*       ws     = (float*)d_ws;

    // ws is re-poisoned to 0xAA before every timed launch -> zero it here.
    const size_t ws_bytes = (size_t)(2 * BATCH * NBIN + BATCH) * sizeof(float);
    hipMemsetAsync(d_ws, 0, ws_bytes, stream);

    dim3 grid(GRIDX, BATCH);
    qap_hist_kernel<<<grid, BLOCK, 0, stream>>>(qX, dXs, labels, ws);
    qap_finalize_kernel<<<1, 64, 0, stream>>>(ws, out);
}